// Round 16
// baseline (143.875 us; speedup 1.0000x reference)
//
#include <hip/hip_runtime.h>
#include <hip/hip_bf16.h>
#include <stdint.h>

typedef unsigned short u16;
typedef __attribute__((ext_vector_type(8))) short short8;
typedef __attribute__((ext_vector_type(4))) float f32x4;

// ---------- helpers ----------
__device__ __forceinline__ uint32_t f2bf(float f) {
    union { float f; uint32_t u; } c; c.f = f;
    uint32_t u = c.u;
    u += 0x7fffu + ((u >> 16) & 1u);   // round-to-nearest-even
    return u >> 16;
}

__device__ __forceinline__ float bf2f(uint32_t u) {
    union { uint32_t u; float f; } c; c.u = u << 16; return c.f;
}

__device__ __forceinline__ void glds16(const void* g, void* l) {
    __builtin_amdgcn_global_load_lds(
        (const __attribute__((address_space(1))) uint32_t*)g,
        (__attribute__((address_space(3))) uint32_t*)l,
        16, 0, 0);
}

// ---------- kernel 1: g_p = FWHT_1024(D_p[:1024] * V) / 1024, for 4 params ----------
__global__ void fwht_g_kernel(const float* __restrict__ V,
                              const float* __restrict__ D0, const float* __restrict__ D1,
                              const float* __restrict__ D2, const float* __restrict__ D3,
                              float* __restrict__ g) {
    __shared__ float s[1024];
    int t = threadIdx.x;
    const float* D = (blockIdx.x == 0) ? D0 : (blockIdx.x == 1) ? D1 :
                     (blockIdx.x == 2) ? D2 : D3;
    s[t] = D[t] * V[t];
    __syncthreads();
    #pragma unroll
    for (int st = 512; st >= 1; st >>= 1) {
        float a = s[t];
        float b = s[t ^ st];
        __syncthreads();
        s[t] = (t & st) ? (b - a) : (a + b);
        __syncthreads();
    }
    g[blockIdx.x * 1024 + t] = s[t] * (1.0f / 1024.0f);
}

// ---------- kernel 2: bias = init + PP * g[i&1023] ----------
__global__ void bias_kernel(const float* __restrict__ init, const float* __restrict__ PP,
                            const float* __restrict__ g, float* __restrict__ out, int n) {
    int i = blockIdx.x * blockDim.x + threadIdx.x;
    if (i < n) out[i] = init[i] + PP[i] * g[i & 1023];
}

// ---------- kernel 3: f32 -> bf16 cast (x), 4 elems/thread ----------
__global__ void cast_kernel(const float* __restrict__ in, u16* __restrict__ out, int n4) {
    int i = blockIdx.x * blockDim.x + threadIdx.x;
    if (i >= n4) return;
    float4 v = ((const float4*)in)[i];
    uint32_t lo = f2bf(v.x) | (f2bf(v.y) << 16);
    uint32_t hi = f2bf(v.z) | (f2bf(v.w) << 16);
    ((uint2*)out)[i] = make_uint2(lo, hi);
}

// ---------- kernel 4: W_bf16 = bf16(W_init + PP * g[idx&1023]), 4 elems/thread ----------
__global__ void wmat_kernel(const float* __restrict__ init, const float* __restrict__ PP,
                            const float* __restrict__ g, u16* __restrict__ out, int n4) {
    int i = blockIdx.x * blockDim.x + threadIdx.x;
    if (i >= n4) return;
    int e = i * 4;
    float4 wi = ((const float4*)init)[i];
    float4 pp = ((const float4*)PP)[i];
    float4 gv = *((const float4*)(g + (e & 1023)));
    uint32_t lo = f2bf(wi.x + pp.x * gv.x) | (f2bf(wi.y + pp.y * gv.y) << 16);
    uint32_t hi = f2bf(wi.z + pp.z * gv.z) | (f2bf(wi.w + pp.w * gv.w) << 16);
    ((uint2*)out)[i] = make_uint2(lo, hi);
}

// ---------- kernel 5: split-K GEMM partial, 2-phase double-buffered ----------
// r14 config (BM=128, BN=64, BK=64, XOR swizzle, bf16 partials) + minimal T3
// 2-phase pipeline: STAGE(buf^1, t+1) issued BEFORE ds_read+MFMA(buf t), one
// vmcnt(0)+barrier per step -> next-tile loads fly under current compute.
// LDS 48 KB -> 3 WG/CU. Grid (N/64, M/128, 4) = 1024 WGs.
__global__ __launch_bounds__(256, 3) void gemm_splitk(const u16* __restrict__ A,
                                                      const u16* __restrict__ B,
                                                      u16* __restrict__ P,
                                                      int M, int N, int K, int Kslice) {
    constexpr int BM = 128, BN = 64, BK = 64;
    __shared__ u16 As[2][BM * BK];   // 2 x 16 KB
    __shared__ u16 Bs[2][BN * BK];   // 2 x 8 KB

    const int t    = threadIdx.x;
    const int wid  = t >> 6;
    const int lane = t & 63;
    const int wr   = wid >> 1;        // 0..1: 64-row block of A
    const int wc   = wid & 1;         // 0..1: 32-col block of B
    const int fr   = lane & 15;
    const int fq   = lane >> 4;
    const int rx   = (fr & 7) << 4;   // read-side swizzle xor (bytes)

    const int bn = blockIdx.x, bm = blockIdx.y, sk = blockIdx.z;
    const int k_beg = sk * Kslice;
    const int nstep = Kslice / BK;

    const u16* Abase = A + (size_t)(bm * BM) * K;
    const u16* Bbase = B + (size_t)(bn * BN) * K;

// stage both tiles for K-step at k0 into buffer d (source col pre-swizzled)
#define STAGE(d, k0) do {                                                         \
        _Pragma("unroll")                                                         \
        for (int q_ = 0; q_ < 4; ++q_) {                                          \
            int L_ = q_ * 256 + t;                                                \
            int row_ = L_ >> 3;                                                   \
            int cg_  = (L_ & 7) ^ (row_ & 7);                                     \
            glds16(Abase + (size_t)row_ * K + (k0) + cg_ * 8, As[d] + L_ * 8);    \
        }                                                                         \
        _Pragma("unroll")                                                         \
        for (int q_ = 0; q_ < 2; ++q_) {                                          \
            int L_ = q_ * 256 + t;                                                \
            int row_ = L_ >> 3;                                                   \
            int cg_  = (L_ & 7) ^ (row_ & 7);                                     \
            glds16(Bbase + (size_t)row_ * K + (k0) + cg_ * 8, Bs[d] + L_ * 8);    \
        }                                                                         \
    } while (0)

    f32x4 acc[4][2];
    #pragma unroll
    for (int m = 0; m < 4; ++m)
        #pragma unroll
        for (int n = 0; n < 2; ++n)
            acc[m][n] = (f32x4){0.f, 0.f, 0.f, 0.f};

    // prologue: tile 0 into buf 0
    STAGE(0, k_beg);
    asm volatile("s_waitcnt vmcnt(0)" ::: "memory");
    __builtin_amdgcn_s_barrier();
    __builtin_amdgcn_sched_barrier(0);

    #pragma unroll 1
    for (int s = 0; s < nstep; ++s) {
        const int d  = s & 1;
        const int k0 = k_beg + s * BK;
        const bool nxt = (s + 1 < nstep);

        if (nxt) STAGE(d ^ 1, k0 + BK);          // issue next-tile loads FIRST
        __builtin_amdgcn_sched_barrier(0);

        // compute on buf d (compiler inserts lgkmcnt for ds_read->MFMA deps)
        const char* Ap = (const char*)As[d];
        const char* Bp = (const char*)Bs[d];
        __builtin_amdgcn_s_setprio(1);
        #pragma unroll
        for (int ks = 0; ks < 2; ++ks) {
            const int co = (ks * 64 + fq * 16) ^ rx;
            short8 a[4], b[2];
            #pragma unroll
            for (int m = 0; m < 4; ++m)
                a[m] = *(const short8*)(Ap + (wr * 64 + m * 16 + fr) * 128 + co);
            #pragma unroll
            for (int n = 0; n < 2; ++n)
                b[n] = *(const short8*)(Bp + (wc * 32 + n * 16 + fr) * 128 + co);
            #pragma unroll
            for (int m = 0; m < 4; ++m)
                #pragma unroll
                for (int n = 0; n < 2; ++n)
                    acc[m][n] = __builtin_amdgcn_mfma_f32_16x16x32_bf16(a[m], b[n], acc[m][n], 0, 0, 0);
        }
        __builtin_amdgcn_s_setprio(0);
        __builtin_amdgcn_sched_barrier(0);

        if (nxt) {
            asm volatile("s_waitcnt vmcnt(0)" ::: "memory");   // next tile landed
            __builtin_amdgcn_s_barrier();                      // all waves done with buf d
            __builtin_amdgcn_sched_barrier(0);
        }
    }
#undef STAGE

    // epilogue: write bf16 partial tile
    u16* Pp = P + (size_t)sk * M * N;
    #pragma unroll
    for (int m = 0; m < 4; ++m) {
        int grow0 = bm * BM + wr * 64 + m * 16 + fq * 4;
        #pragma unroll
        for (int n = 0; n < 2; ++n) {
            int gcol = bn * BN + wc * 32 + n * 16 + fr;
            #pragma unroll
            for (int j = 0; j < 4; ++j)
                Pp[(size_t)(grow0 + j) * N + gcol] = (u16)f2bf(acc[m][n][j]);
        }
    }
}

// ---------- kernel 6: reduce S bf16 partials + bias (+relu) -> bf16 or f32 ----------
template <typename OutT, bool RELU, int S>
__global__ void reduce_kernel(const u16* __restrict__ P, const float* __restrict__ bias,
                              OutT* __restrict__ out, int MN, int N) {
    int i = blockIdx.x * blockDim.x + threadIdx.x;   // handles 8 elems
    if (i * 8 >= MN) return;
    int e = i * 8;
    int col = e & (N - 1);

    float a0 = 0.f, a1 = 0.f, a2 = 0.f, a3 = 0.f, a4 = 0.f, a5 = 0.f, a6 = 0.f, a7 = 0.f;
    #pragma unroll
    for (int s = 0; s < S; ++s) {
        uint4 v = ((const uint4*)(P + (size_t)s * MN))[i];
        a0 += bf2f(v.x & 0xffffu);  a1 += bf2f(v.x >> 16);
        a2 += bf2f(v.y & 0xffffu);  a3 += bf2f(v.y >> 16);
        a4 += bf2f(v.z & 0xffffu);  a5 += bf2f(v.z >> 16);
        a6 += bf2f(v.w & 0xffffu);  a7 += bf2f(v.w >> 16);
    }
    float4 bv0 = ((const float4*)(bias + col))[0];
    float4 bv1 = ((const float4*)(bias + col))[1];
    a0 += bv0.x; a1 += bv0.y; a2 += bv0.z; a3 += bv0.w;
    a4 += bv1.x; a5 += bv1.y; a6 += bv1.z; a7 += bv1.w;
    if (RELU) {
        a0 = fmaxf(a0, 0.f); a1 = fmaxf(a1, 0.f); a2 = fmaxf(a2, 0.f); a3 = fmaxf(a3, 0.f);
        a4 = fmaxf(a4, 0.f); a5 = fmaxf(a5, 0.f); a6 = fmaxf(a6, 0.f); a7 = fmaxf(a7, 0.f);
    }
    if constexpr (sizeof(OutT) == 2) {
        uint4 r;
        r.x = f2bf(a0) | (f2bf(a1) << 16);
        r.y = f2bf(a2) | (f2bf(a3) << 16);
        r.z = f2bf(a4) | (f2bf(a5) << 16);
        r.w = f2bf(a6) | (f2bf(a7) << 16);
        ((uint4*)out)[i] = r;
    } else {
        float4 o0 = {a0, a1, a2, a3};
        float4 o1 = {a4, a5, a6, a7};
        ((float4*)out)[i * 2]     = o0;
        ((float4*)out)[i * 2 + 1] = o1;
    }
}

// ---------- launch ----------
extern "C" void kernel_launch(void* const* d_in, const int* in_sizes, int n_in,
                              void* d_out, int out_size, void* d_ws, size_t ws_size,
                              hipStream_t stream) {
    (void)in_sizes; (void)n_in; (void)out_size; (void)ws_size;

    const float* x       = (const float*)d_in[0];
    const float* V       = (const float*)d_in[1];
    const float* W1_init = (const float*)d_in[2];
    const float* D_W1    = (const float*)d_in[3];
    const float* PP_W1   = (const float*)d_in[4];
    const float* b1_init = (const float*)d_in[5];
    const float* D_b1    = (const float*)d_in[6];
    const float* PP_b1   = (const float*)d_in[7];
    const float* W2_init = (const float*)d_in[8];
    const float* D_W2    = (const float*)d_in[9];
    const float* PP_W2   = (const float*)d_in[10];
    const float* b2_init = (const float*)d_in[11];
    const float* D_b2    = (const float*)d_in[12];
    const float* PP_b2   = (const float*)d_in[13];

    constexpr size_t MB = 1024 * 1024;
    char* ws = (char*)d_ws;
    float* g    = (float*)(ws);                      // 4x1024 f32: [W1 | b1 | W2 | b2]
    float* b1w  = (float*)(ws + 16384);              // 4096 f32
    float* b2w  = (float*)(ws + 32768);              // 4096 f32
    u16*   xb   = (u16*)(ws + 65536);                // 512x4096 bf16 (4 MB)
    u16*   hb   = (u16*)(ws + 65536 + 4 * MB);       // 512x4096 bf16 (4 MB)
    u16*   wbuf = (u16*)(ws + 65536 + 8 * MB);       // 32 MB: W1 then W2
    u16*   Pbuf = (u16*)(ws + 65536 + 40 * MB);      // 4x512x4096 bf16 (16 MB)

    const int M = 512, N = 4096, K = 4096, S = 4, Kslice = K / S;

    fwht_g_kernel<<<4, 1024, 0, stream>>>(V, D_W1, D_b1, D_W2, D_b2, g);
    bias_kernel<<<4, 1024, 0, stream>>>(b1_init, PP_b1, g + 1024, b1w, 4096);
    bias_kernel<<<4, 1024, 0, stream>>>(b2_init, PP_b2, g + 3072, b2w, 4096);
    cast_kernel<<<2048, 256, 0, stream>>>(x, xb, M * K / 4);

    // layer 1: materialize W1, 2-phase pipelined GEMM, reduce
    wmat_kernel<<<16384, 256, 0, stream>>>(W1_init, PP_W1, g, wbuf, 4096 * 4096 / 4);
    gemm_splitk<<<dim3(N / 64, M / 128, S), 256, 0, stream>>>(xb, wbuf, Pbuf, M, N, K, Kslice);
    reduce_kernel<u16, true, S><<<M * N / 8 / 256, 256, 0, stream>>>(Pbuf, b1w, hb, M * N, N);

    // layer 2 (wbuf, Pbuf reused)
    wmat_kernel<<<16384, 256, 0, stream>>>(W2_init, PP_W2, g + 2048, wbuf, 4096 * 4096 / 4);
    gemm_splitk<<<dim3(N / 64, M / 128, S), 256, 0, stream>>>(hb, wbuf, Pbuf, M, N, K, Kslice);
    reduce_kernel<float, false, S><<<M * N / 8 / 256, 256, 0, stream>>>(Pbuf, b2w, (float*)d_out, M * N, N);
}

// Round 17
// 136.452 us; speedup vs baseline: 1.0544x; 1.0544x over previous
//
#include <hip/hip_runtime.h>
#include <hip/hip_bf16.h>
#include <stdint.h>

typedef unsigned short u16;
typedef __attribute__((ext_vector_type(8))) short short8;
typedef __attribute__((ext_vector_type(4))) float f32x4;

// ---------- helpers ----------
__device__ __forceinline__ uint32_t f2bf(float f) {
    union { float f; uint32_t u; } c; c.f = f;
    uint32_t u = c.u;
    u += 0x7fffu + ((u >> 16) & 1u);   // round-to-nearest-even
    return u >> 16;
}

__device__ __forceinline__ float bf2f(uint32_t u) {
    union { uint32_t u; float f; } c; c.u = u << 16; return c.f;
}

__device__ __forceinline__ void glds16(const void* g, void* l) {
    __builtin_amdgcn_global_load_lds(
        (const __attribute__((address_space(1))) uint32_t*)g,
        (__attribute__((address_space(3))) uint32_t*)l,
        16, 0, 0);
}

// ---------- kernel 1: g_p = FWHT_1024(D_p[:1024] * V) / 1024, for 4 params ----------
__global__ void fwht_g_kernel(const float* __restrict__ V,
                              const float* __restrict__ D0, const float* __restrict__ D1,
                              const float* __restrict__ D2, const float* __restrict__ D3,
                              float* __restrict__ g) {
    __shared__ float s[1024];
    int t = threadIdx.x;
    const float* D = (blockIdx.x == 0) ? D0 : (blockIdx.x == 1) ? D1 :
                     (blockIdx.x == 2) ? D2 : D3;
    s[t] = D[t] * V[t];
    __syncthreads();
    #pragma unroll
    for (int st = 512; st >= 1; st >>= 1) {
        float a = s[t];
        float b = s[t ^ st];
        __syncthreads();
        s[t] = (t & st) ? (b - a) : (a + b);
        __syncthreads();
    }
    g[blockIdx.x * 1024 + t] = s[t] * (1.0f / 1024.0f);
}

// ---------- kernel 2: bias = init + PP * g[i&1023] ----------
__global__ void bias_kernel(const float* __restrict__ init, const float* __restrict__ PP,
                            const float* __restrict__ g, float* __restrict__ out, int n) {
    int i = blockIdx.x * blockDim.x + threadIdx.x;
    if (i < n) out[i] = init[i] + PP[i] * g[i & 1023];
}

// ---------- kernel 3: f32 -> bf16 cast (x), 4 elems/thread ----------
__global__ void cast_kernel(const float* __restrict__ in, u16* __restrict__ out, int n4) {
    int i = blockIdx.x * blockDim.x + threadIdx.x;
    if (i >= n4) return;
    float4 v = ((const float4*)in)[i];
    uint32_t lo = f2bf(v.x) | (f2bf(v.y) << 16);
    uint32_t hi = f2bf(v.z) | (f2bf(v.w) << 16);
    ((uint2*)out)[i] = make_uint2(lo, hi);
}

// ---------- kernel 4: W_bf16 = bf16(W_init + PP * g[idx&1023]), 4 elems/thread ----------
__global__ void wmat_kernel(const float* __restrict__ init, const float* __restrict__ PP,
                            const float* __restrict__ g, u16* __restrict__ out, int n4) {
    int i = blockIdx.x * blockDim.x + threadIdx.x;
    if (i >= n4) return;
    int e = i * 4;
    float4 wi = ((const float4*)init)[i];
    float4 pp = ((const float4*)PP)[i];
    float4 gv = *((const float4*)(g + (e & 1023)));
    uint32_t lo = f2bf(wi.x + pp.x * gv.x) | (f2bf(wi.y + pp.y * gv.y) << 16);
    uint32_t hi = f2bf(wi.z + pp.z * gv.z) | (f2bf(wi.w + pp.w * gv.w) << 16);
    ((uint2*)out)[i] = make_uint2(lo, hi);
}

// ---------- kernel 5: split-K GEMM partial: P[s] = A(MxKs) @ B^T(NxKs), bf16 out ----------
// Max-TLP variant: BM=64, BN=64, BK=64, LDS 16 KB -> 8 WG/CU = 32 waves/CU (HW max).
// Grid (N/64, M/64, 4) = 2048 WGs = 8/CU resident. XOR swizzle both tiles.
// 4 waves 2x2: wave tile 32x32, acc[2][2] (8 MFMA/wave/step, ~52 VGPR under the
// 64-cap of __launch_bounds__(256,8)). bf16 partials (r14-validated).
__global__ __launch_bounds__(256, 8) void gemm_splitk(const u16* __restrict__ A,
                                                      const u16* __restrict__ B,
                                                      u16* __restrict__ P,
                                                      int M, int N, int K, int Kslice) {
    constexpr int BM = 64, BN = 64, BK = 64;
    __shared__ u16 As[BM * BK];   // 8 KB
    __shared__ u16 Bs[BN * BK];   // 8 KB

    const int t    = threadIdx.x;
    const int wid  = t >> 6;
    const int lane = t & 63;
    const int wr   = wid >> 1;        // 0..1: 32-row block of A
    const int wc   = wid & 1;         // 0..1: 32-col block of B
    const int fr   = lane & 15;
    const int fq   = lane >> 4;
    const int rx   = (fr & 7) << 4;   // read-side swizzle xor (bytes)

    const int bn = blockIdx.x, bm = blockIdx.y, sk = blockIdx.z;
    const int k_beg = sk * Kslice;

    const u16* Abase = A + (size_t)(bm * BM) * K;
    const u16* Bbase = B + (size_t)(bn * BN) * K;

    f32x4 acc[2][2];
    #pragma unroll
    for (int m = 0; m < 2; ++m)
        #pragma unroll
        for (int n = 0; n < 2; ++n)
            acc[m][n] = (f32x4){0.f, 0.f, 0.f, 0.f};

    #pragma unroll 1
    for (int k0 = k_beg; k0 < k_beg + Kslice; k0 += BK) {
        // stage A: 64x64 = 512 16B-chunks = 2 rounds; source col pre-swizzled
        #pragma unroll
        for (int q = 0; q < 2; ++q) {
            int L = q * 256 + t;
            int row = L >> 3;
            int cg  = (L & 7) ^ (row & 7);
            glds16(Abase + (size_t)row * K + k0 + cg * 8, As + L * 8);
        }
        // stage B: 64x64 = 512 chunks = 2 rounds
        #pragma unroll
        for (int q = 0; q < 2; ++q) {
            int L = q * 256 + t;
            int row = L >> 3;
            int cg  = (L & 7) ^ (row & 7);
            glds16(Bbase + (size_t)row * K + k0 + cg * 8, Bs + L * 8);
        }
        __syncthreads();

        const char* Ap = (const char*)As;
        const char* Bp = (const char*)Bs;
        __builtin_amdgcn_s_setprio(1);
        #pragma unroll
        for (int ks = 0; ks < 2; ++ks) {
            const int co = (ks * 64 + fq * 16) ^ rx;
            short8 a[2], b[2];
            #pragma unroll
            for (int m = 0; m < 2; ++m)
                a[m] = *(const short8*)(Ap + (wr * 32 + m * 16 + fr) * 128 + co);
            #pragma unroll
            for (int n = 0; n < 2; ++n)
                b[n] = *(const short8*)(Bp + (wc * 32 + n * 16 + fr) * 128 + co);
            #pragma unroll
            for (int m = 0; m < 2; ++m)
                #pragma unroll
                for (int n = 0; n < 2; ++n)
                    acc[m][n] = __builtin_amdgcn_mfma_f32_16x16x32_bf16(a[m], b[n], acc[m][n], 0, 0, 0);
        }
        __builtin_amdgcn_s_setprio(0);
        __syncthreads();
    }

    // epilogue: write bf16 partial tile
    u16* Pp = P + (size_t)sk * M * N;
    #pragma unroll
    for (int m = 0; m < 2; ++m) {
        int grow0 = bm * BM + wr * 32 + m * 16 + fq * 4;
        #pragma unroll
        for (int n = 0; n < 2; ++n) {
            int gcol = bn * BN + wc * 32 + n * 16 + fr;
            #pragma unroll
            for (int j = 0; j < 4; ++j)
                Pp[(size_t)(grow0 + j) * N + gcol] = (u16)f2bf(acc[m][n][j]);
        }
    }
}

// ---------- kernel 6: reduce S bf16 partials + bias (+relu) -> bf16 or f32 ----------
template <typename OutT, bool RELU, int S>
__global__ void reduce_kernel(const u16* __restrict__ P, const float* __restrict__ bias,
                              OutT* __restrict__ out, int MN, int N) {
    int i = blockIdx.x * blockDim.x + threadIdx.x;   // handles 8 elems
    if (i * 8 >= MN) return;
    int e = i * 8;
    int col = e & (N - 1);

    float a0 = 0.f, a1 = 0.f, a2 = 0.f, a3 = 0.f, a4 = 0.f, a5 = 0.f, a6 = 0.f, a7 = 0.f;
    #pragma unroll
    for (int s = 0; s < S; ++s) {
        uint4 v = ((const uint4*)(P + (size_t)s * MN))[i];
        a0 += bf2f(v.x & 0xffffu);  a1 += bf2f(v.x >> 16);
        a2 += bf2f(v.y & 0xffffu);  a3 += bf2f(v.y >> 16);
        a4 += bf2f(v.z & 0xffffu);  a5 += bf2f(v.z >> 16);
        a6 += bf2f(v.w & 0xffffu);  a7 += bf2f(v.w >> 16);
    }
    float4 bv0 = ((const float4*)(bias + col))[0];
    float4 bv1 = ((const float4*)(bias + col))[1];
    a0 += bv0.x; a1 += bv0.y; a2 += bv0.z; a3 += bv0.w;
    a4 += bv1.x; a5 += bv1.y; a6 += bv1.z; a7 += bv1.w;
    if (RELU) {
        a0 = fmaxf(a0, 0.f); a1 = fmaxf(a1, 0.f); a2 = fmaxf(a2, 0.f); a3 = fmaxf(a3, 0.f);
        a4 = fmaxf(a4, 0.f); a5 = fmaxf(a5, 0.f); a6 = fmaxf(a6, 0.f); a7 = fmaxf(a7, 0.f);
    }
    if constexpr (sizeof(OutT) == 2) {
        uint4 r;
        r.x = f2bf(a0) | (f2bf(a1) << 16);
        r.y = f2bf(a2) | (f2bf(a3) << 16);
        r.z = f2bf(a4) | (f2bf(a5) << 16);
        r.w = f2bf(a6) | (f2bf(a7) << 16);
        ((uint4*)out)[i] = r;
    } else {
        float4 o0 = {a0, a1, a2, a3};
        float4 o1 = {a4, a5, a6, a7};
        ((float4*)out)[i * 2]     = o0;
        ((float4*)out)[i * 2 + 1] = o1;
    }
}

// ---------- launch ----------
extern "C" void kernel_launch(void* const* d_in, const int* in_sizes, int n_in,
                              void* d_out, int out_size, void* d_ws, size_t ws_size,
                              hipStream_t stream) {
    (void)in_sizes; (void)n_in; (void)out_size; (void)ws_size;

    const float* x       = (const float*)d_in[0];
    const float* V       = (const float*)d_in[1];
    const float* W1_init = (const float*)d_in[2];
    const float* D_W1    = (const float*)d_in[3];
    const float* PP_W1   = (const float*)d_in[4];
    const float* b1_init = (const float*)d_in[5];
    const float* D_b1    = (const float*)d_in[6];
    const float* PP_b1   = (const float*)d_in[7];
    const float* W2_init = (const float*)d_in[8];
    const float* D_W2    = (const float*)d_in[9];
    const float* PP_W2   = (const float*)d_in[10];
    const float* b2_init = (const float*)d_in[11];
    const float* D_b2    = (const float*)d_in[12];
    const float* PP_b2   = (const float*)d_in[13];

    constexpr size_t MB = 1024 * 1024;
    char* ws = (char*)d_ws;
    float* g    = (float*)(ws);                      // 4x1024 f32: [W1 | b1 | W2 | b2]
    float* b1w  = (float*)(ws + 16384);              // 4096 f32
    float* b2w  = (float*)(ws + 32768);              // 4096 f32
    u16*   xb   = (u16*)(ws + 65536);                // 512x4096 bf16 (4 MB)
    u16*   hb   = (u16*)(ws + 65536 + 4 * MB);       // 512x4096 bf16 (4 MB)
    u16*   wbuf = (u16*)(ws + 65536 + 8 * MB);       // 32 MB: W1 then W2
    u16*   Pbuf = (u16*)(ws + 65536 + 40 * MB);      // 4x512x4096 bf16 (16 MB)

    const int M = 512, N = 4096, K = 4096, S = 4, Kslice = K / S;

    fwht_g_kernel<<<4, 1024, 0, stream>>>(V, D_W1, D_b1, D_W2, D_b2, g);
    bias_kernel<<<4, 1024, 0, stream>>>(b1_init, PP_b1, g + 1024, b1w, 4096);
    bias_kernel<<<4, 1024, 0, stream>>>(b2_init, PP_b2, g + 3072, b2w, 4096);
    cast_kernel<<<2048, 256, 0, stream>>>(x, xb, M * K / 4);

    // layer 1: materialize W1, GEMM at 8 WG/CU (2048 WGs), reduce
    wmat_kernel<<<16384, 256, 0, stream>>>(W1_init, PP_W1, g, wbuf, 4096 * 4096 / 4);
    gemm_splitk<<<dim3(N / 64, M / 64, S), 256, 0, stream>>>(xb, wbuf, Pbuf, M, N, K, Kslice);
    reduce_kernel<u16, true, S><<<M * N / 8 / 256, 256, 0, stream>>>(Pbuf, b1w, hb, M * N, N);

    // layer 2 (wbuf, Pbuf reused)
    wmat_kernel<<<16384, 256, 0, stream>>>(W2_init, PP_W2, g + 2048, wbuf, 4096 * 4096 / 4);
    gemm_splitk<<<dim3(N / 64, M / 64, S), 256, 0, stream>>>(hb, wbuf, Pbuf, M, N, K, Kslice);
    reduce_kernel<float, false, S><<<M * N / 8 / 256, 256, 0, stream>>>(Pbuf, b2w, (float*)d_out, M * N, N);
}

// Round 18
// 136.258 us; speedup vs baseline: 1.0559x; 1.0014x over previous
//
#include <hip/hip_runtime.h>
#include <hip/hip_bf16.h>
#include <stdint.h>

typedef unsigned short u16;
typedef __attribute__((ext_vector_type(8))) short short8;
typedef __attribute__((ext_vector_type(4))) float f32x4;

// ---------- helpers ----------
__device__ __forceinline__ uint32_t f2bf(float f) {
    union { float f; uint32_t u; } c; c.f = f;
    uint32_t u = c.u;
    u += 0x7fffu + ((u >> 16) & 1u);   // round-to-nearest-even
    return u >> 16;
}

__device__ __forceinline__ float bf2f(uint32_t u) {
    union { uint32_t u; float f; } c; c.u = u << 16; return c.f;
}

__device__ __forceinline__ void glds16(const void* g, void* l) {
    __builtin_amdgcn_global_load_lds(
        (const __attribute__((address_space(1))) uint32_t*)g,
        (__attribute__((address_space(3))) uint32_t*)l,
        16, 0, 0);
}

// ---------- kernel 1: g_p = FWHT_1024(D_p[:1024] * V) / 1024, for 4 params ----------
__global__ void fwht_g_kernel(const float* __restrict__ V,
                              const float* __restrict__ D0, const float* __restrict__ D1,
                              const float* __restrict__ D2, const float* __restrict__ D3,
                              float* __restrict__ g) {
    __shared__ float s[1024];
    int t = threadIdx.x;
    const float* D = (blockIdx.x == 0) ? D0 : (blockIdx.x == 1) ? D1 :
                     (blockIdx.x == 2) ? D2 : D3;
    s[t] = D[t] * V[t];
    __syncthreads();
    #pragma unroll
    for (int st = 512; st >= 1; st >>= 1) {
        float a = s[t];
        float b = s[t ^ st];
        __syncthreads();
        s[t] = (t & st) ? (b - a) : (a + b);
        __syncthreads();
    }
    g[blockIdx.x * 1024 + t] = s[t] * (1.0f / 1024.0f);
}

// ---------- kernel 2: bias = init + PP * g[i&1023] ----------
__global__ void bias_kernel(const float* __restrict__ init, const float* __restrict__ PP,
                            const float* __restrict__ g, float* __restrict__ out, int n) {
    int i = blockIdx.x * blockDim.x + threadIdx.x;
    if (i < n) out[i] = init[i] + PP[i] * g[i & 1023];
}

// ---------- kernel 3: f32 -> bf16 cast (x), 4 elems/thread ----------
__global__ void cast_kernel(const float* __restrict__ in, u16* __restrict__ out, int n4) {
    int i = blockIdx.x * blockDim.x + threadIdx.x;
    if (i >= n4) return;
    float4 v = ((const float4*)in)[i];
    uint32_t lo = f2bf(v.x) | (f2bf(v.y) << 16);
    uint32_t hi = f2bf(v.z) | (f2bf(v.w) << 16);
    ((uint2*)out)[i] = make_uint2(lo, hi);
}

// ---------- kernel 4: W_bf16 = bf16(W_init + PP * g[idx&1023]), 4 elems/thread ----------
__global__ void wmat_kernel(const float* __restrict__ init, const float* __restrict__ PP,
                            const float* __restrict__ g, u16* __restrict__ out, int n4) {
    int i = blockIdx.x * blockDim.x + threadIdx.x;
    if (i >= n4) return;
    int e = i * 4;
    float4 wi = ((const float4*)init)[i];
    float4 pp = ((const float4*)PP)[i];
    float4 gv = *((const float4*)(g + (e & 1023)));
    uint32_t lo = f2bf(wi.x + pp.x * gv.x) | (f2bf(wi.y + pp.y * gv.y) << 16);
    uint32_t hi = f2bf(wi.z + pp.z * gv.z) | (f2bf(wi.w + pp.w * gv.w) << 16);
    ((uint2*)out)[i] = make_uint2(lo, hi);
}

// ---------- kernel 5: split-K GEMM, counted-vmcnt double-buffer (T3/T4 minimum) ----------
// r14 tile (BM=128, BN=64, BK=64, XOR swizzle, bf16 partials). Per step s, buf d:
//   ds_read 12 frags (tile s) -> regs; lgkmcnt(0)+barrier (cheap);
//   STAGE(d, s+2) (6 glds into vacated buf); MFMA from regs;
//   vmcnt(6)+barrier -> tile s+1 (issued a full step ago) landed, s+2 stays in flight.
// No naked drain of just-issued loads anywhere. LDS 48 KB -> 3 WG/CU, grid 1024 WGs.
__global__ __launch_bounds__(256, 3) void gemm_splitk(const u16* __restrict__ A,
                                                      const u16* __restrict__ B,
                                                      u16* __restrict__ P,
                                                      int M, int N, int K, int Kslice) {
    constexpr int BM = 128, BN = 64, BK = 64;
    __shared__ u16 As[2][BM * BK];   // 2 x 16 KB
    __shared__ u16 Bs[2][BN * BK];   // 2 x 8 KB

    const int t    = threadIdx.x;
    const int wid  = t >> 6;
    const int lane = t & 63;
    const int wr   = wid >> 1;        // 0..1: 64-row block of A
    const int wc   = wid & 1;         // 0..1: 32-col block of B
    const int fr   = lane & 15;
    const int fq   = lane >> 4;
    const int rx   = (fr & 7) << 4;   // read-side swizzle xor (bytes)

    const int bn = blockIdx.x, bm = blockIdx.y, sk = blockIdx.z;
    const int k_beg = sk * Kslice;
    const int nstep = Kslice / BK;    // 16

    const u16* Abase = A + (size_t)(bm * BM) * K;
    const u16* Bbase = B + (size_t)(bn * BN) * K;

// stage tile at k0 into buffer d: 4 A-glds + 2 B-glds per thread (src pre-swizzled)
#define STAGE(d, k0) do {                                                         \
        _Pragma("unroll")                                                         \
        for (int q_ = 0; q_ < 4; ++q_) {                                          \
            int L_ = q_ * 256 + t;                                                \
            int row_ = L_ >> 3;                                                   \
            int cg_  = (L_ & 7) ^ (row_ & 7);                                     \
            glds16(Abase + (size_t)row_ * K + (k0) + cg_ * 8, As[d] + L_ * 8);    \
        }                                                                         \
        _Pragma("unroll")                                                         \
        for (int q_ = 0; q_ < 2; ++q_) {                                          \
            int L_ = q_ * 256 + t;                                                \
            int row_ = L_ >> 3;                                                   \
            int cg_  = (L_ & 7) ^ (row_ & 7);                                     \
            glds16(Bbase + (size_t)row_ * K + (k0) + cg_ * 8, Bs[d] + L_ * 8);    \
        }                                                                         \
    } while (0)

    f32x4 acc[4][2];
    #pragma unroll
    for (int m = 0; m < 4; ++m)
        #pragma unroll
        for (int n = 0; n < 2; ++n)
            acc[m][n] = (f32x4){0.f, 0.f, 0.f, 0.f};

    // ---- prologue: tiles 0,1 in flight; wait tile 0 only (vmcnt(6)) ----
    STAGE(0, k_beg);
    STAGE(1, k_beg + BK);
    asm volatile("s_waitcnt vmcnt(6)" ::: "memory");
    __builtin_amdgcn_s_barrier();
    __builtin_amdgcn_sched_barrier(0);

    #pragma unroll 1
    for (int s = 0; s < nstep; ++s) {
        const int d = s & 1;
        int k2 = k_beg + (s + 2) * BK;
        if (s + 2 >= nstep) k2 = k_beg;          // dummy: keeps 6-per-step invariant

        // phase 1: read ALL frags of tile s into registers (buf d)
        const char* Ap = (const char*)As[d];
        const char* Bp = (const char*)Bs[d];
        short8 a0[4], b0[2], a1[4], b1[2];
        {
            const int co0 = (fq * 16) ^ rx;
            const int co1 = (64 + fq * 16) ^ rx;
            #pragma unroll
            for (int m = 0; m < 4; ++m) {
                a0[m] = *(const short8*)(Ap + (wr * 64 + m * 16 + fr) * 128 + co0);
                a1[m] = *(const short8*)(Ap + (wr * 64 + m * 16 + fr) * 128 + co1);
            }
            #pragma unroll
            for (int n = 0; n < 2; ++n) {
                b0[n] = *(const short8*)(Bp + (wc * 32 + n * 16 + fr) * 128 + co0);
                b1[n] = *(const short8*)(Bp + (wc * 32 + n * 16 + fr) * 128 + co1);
            }
        }
        __builtin_amdgcn_sched_barrier(0);
        asm volatile("s_waitcnt lgkmcnt(0)" ::: "memory");   // this wave's reads done
        __builtin_amdgcn_sched_barrier(0);
        __builtin_amdgcn_s_barrier();                        // ALL waves' reads done
        __builtin_amdgcn_sched_barrier(0);

        // phase 2: refill vacated buffer with tile s+2 (loads fly under MFMA + next step)
        STAGE(d, k2);
        __builtin_amdgcn_sched_barrier(0);

        // phase 3: MFMA from registers (same accumulation order as r14: ks=0 then ks=1)
        __builtin_amdgcn_s_setprio(1);
        #pragma unroll
        for (int m = 0; m < 4; ++m)
            #pragma unroll
            for (int n = 0; n < 2; ++n)
                acc[m][n] = __builtin_amdgcn_mfma_f32_16x16x32_bf16(a0[m], b0[n], acc[m][n], 0, 0, 0);
        #pragma unroll
        for (int m = 0; m < 4; ++m)
            #pragma unroll
            for (int n = 0; n < 2; ++n)
                acc[m][n] = __builtin_amdgcn_mfma_f32_16x16x32_bf16(a1[m], b1[n], acc[m][n], 0, 0, 0);
        __builtin_amdgcn_s_setprio(0);
        __builtin_amdgcn_sched_barrier(0);

        // phase 4: counted wait — tile s+1 (issued a full step ago) must be landed;
        // tile s+2's 6 loads stay in flight across the barrier. Never drain to 0.
        asm volatile("s_waitcnt vmcnt(6)" ::: "memory");
        __builtin_amdgcn_s_barrier();
        __builtin_amdgcn_sched_barrier(0);
    }
#undef STAGE

    // epilogue: write bf16 partial tile
    u16* Pp = P + (size_t)sk * M * N;
    #pragma unroll
    for (int m = 0; m < 4; ++m) {
        int grow0 = bm * BM + wr * 64 + m * 16 + fq * 4;
        #pragma unroll
        for (int n = 0; n < 2; ++n) {
            int gcol = bn * BN + wc * 32 + n * 16 + fr;
            #pragma unroll
            for (int j = 0; j < 4; ++j)
                Pp[(size_t)(grow0 + j) * N + gcol] = (u16)f2bf(acc[m][n][j]);
        }
    }
}

// ---------- kernel 6: reduce S bf16 partials + bias (+relu) -> bf16 or f32 ----------
template <typename OutT, bool RELU, int S>
__global__ void reduce_kernel(const u16* __restrict__ P, const float* __restrict__ bias,
                              OutT* __restrict__ out, int MN, int N) {
    int i = blockIdx.x * blockDim.x + threadIdx.x;   // handles 8 elems
    if (i * 8 >= MN) return;
    int e = i * 8;
    int col = e & (N - 1);

    float a0 = 0.f, a1 = 0.f, a2 = 0.f, a3 = 0.f, a4 = 0.f, a5 = 0.f, a6 = 0.f, a7 = 0.f;
    #pragma unroll
    for (int s = 0; s < S; ++s) {
        uint4 v = ((const uint4*)(P + (size_t)s * MN))[i];
        a0 += bf2f(v.x & 0xffffu);  a1 += bf2f(v.x >> 16);
        a2 += bf2f(v.y & 0xffffu);  a3 += bf2f(v.y >> 16);
        a4 += bf2f(v.z & 0xffffu);  a5 += bf2f(v.z >> 16);
        a6 += bf2f(v.w & 0xffffu);  a7 += bf2f(v.w >> 16);
    }
    float4 bv0 = ((const float4*)(bias + col))[0];
    float4 bv1 = ((const float4*)(bias + col))[1];
    a0 += bv0.x; a1 += bv0.y; a2 += bv0.z; a3 += bv0.w;
    a4 += bv1.x; a5 += bv1.y; a6 += bv1.z; a7 += bv1.w;
    if (RELU) {
        a0 = fmaxf(a0, 0.f); a1 = fmaxf(a1, 0.f); a2 = fmaxf(a2, 0.f); a3 = fmaxf(a3, 0.f);
        a4 = fmaxf(a4, 0.f); a5 = fmaxf(a5, 0.f); a6 = fmaxf(a6, 0.f); a7 = fmaxf(a7, 0.f);
    }
    if constexpr (sizeof(OutT) == 2) {
        uint4 r;
        r.x = f2bf(a0) | (f2bf(a1) << 16);
        r.y = f2bf(a2) | (f2bf(a3) << 16);
        r.z = f2bf(a4) | (f2bf(a5) << 16);
        r.w = f2bf(a6) | (f2bf(a7) << 16);
        ((uint4*)out)[i] = r;
    } else {
        float4 o0 = {a0, a1, a2, a3};
        float4 o1 = {a4, a5, a6, a7};
        ((float4*)out)[i * 2]     = o0;
        ((float4*)out)[i * 2 + 1] = o1;
    }
}

// ---------- launch ----------
extern "C" void kernel_launch(void* const* d_in, const int* in_sizes, int n_in,
                              void* d_out, int out_size, void* d_ws, size_t ws_size,
                              hipStream_t stream) {
    (void)in_sizes; (void)n_in; (void)out_size; (void)ws_size;

    const float* x       = (const float*)d_in[0];
    const float* V       = (const float*)d_in[1];
    const float* W1_init = (const float*)d_in[2];
    const float* D_W1    = (const float*)d_in[3];
    const float* PP_W1   = (const float*)d_in[4];
    const float* b1_init = (const float*)d_in[5];
    const float* D_b1    = (const float*)d_in[6];
    const float* PP_b1   = (const float*)d_in[7];
    const float* W2_init = (const float*)d_in[8];
    const float* D_W2    = (const float*)d_in[9];
    const float* PP_W2   = (const float*)d_in[10];
    const float* b2_init = (const float*)d_in[11];
    const float* D_b2    = (const float*)d_in[12];
    const float* PP_b2   = (const float*)d_in[13];

    constexpr size_t MB = 1024 * 1024;
    char* ws = (char*)d_ws;
    float* g    = (float*)(ws);                      // 4x1024 f32: [W1 | b1 | W2 | b2]
    float* b1w  = (float*)(ws + 16384);              // 4096 f32
    float* b2w  = (float*)(ws + 32768);              // 4096 f32
    u16*   xb   = (u16*)(ws + 65536);                // 512x4096 bf16 (4 MB)
    u16*   hb   = (u16*)(ws + 65536 + 4 * MB);       // 512x4096 bf16 (4 MB)
    u16*   wbuf = (u16*)(ws + 65536 + 8 * MB);       // 32 MB: W1 then W2
    u16*   Pbuf = (u16*)(ws + 65536 + 40 * MB);      // 4x512x4096 bf16 (16 MB)

    const int M = 512, N = 4096, K = 4096, S = 4, Kslice = K / S;

    fwht_g_kernel<<<4, 1024, 0, stream>>>(V, D_W1, D_b1, D_W2, D_b2, g);
    bias_kernel<<<4, 1024, 0, stream>>>(b1_init, PP_b1, g + 1024, b1w, 4096);
    bias_kernel<<<4, 1024, 0, stream>>>(b2_init, PP_b2, g + 3072, b2w, 4096);
    cast_kernel<<<2048, 256, 0, stream>>>(x, xb, M * K / 4);

    // layer 1: materialize W1, counted-vmcnt dbuf GEMM, reduce
    wmat_kernel<<<16384, 256, 0, stream>>>(W1_init, PP_W1, g, wbuf, 4096 * 4096 / 4);
    gemm_splitk<<<dim3(N / 64, M / 128, S), 256, 0, stream>>>(xb, wbuf, Pbuf, M, N, K, Kslice);
    reduce_kernel<u16, true, S><<<M * N / 8 / 256, 256, 0, stream>>>(Pbuf, b1w, hb, M * N, N);

    // layer 2 (wbuf, Pbuf reused)
    wmat_kernel<<<16384, 256, 0, stream>>>(W2_init, PP_W2, g + 2048, wbuf, 4096 * 4096 / 4);
    gemm_splitk<<<dim3(N / 64, M / 128, S), 256, 0, stream>>>(hb, wbuf, Pbuf, M, N, K, Kslice);
    reduce_kernel<float, false, S><<<M * N / 8 / 256, 256, 0, stream>>>(Pbuf, b2w, (float*)d_out, M * N, N);
}

// Round 19
// 122.376 us; speedup vs baseline: 1.1757x; 1.1134x over previous
//
#include <hip/hip_runtime.h>
#include <hip/hip_bf16.h>
#include <stdint.h>

typedef unsigned short u16;
typedef __attribute__((ext_vector_type(8))) short short8;
typedef __attribute__((ext_vector_type(4))) float f32x4;

// ---------- helpers ----------
__device__ __forceinline__ uint32_t f2bf(float f) {
    union { float f; uint32_t u; } c; c.f = f;
    uint32_t u = c.u;
    u += 0x7fffu + ((u >> 16) & 1u);   // round-to-nearest-even
    return u >> 16;
}

__device__ __forceinline__ float bf2f(uint32_t u) {
    union { uint32_t u; float f; } c; c.u = u << 16; return c.f;
}

__device__ __forceinline__ void glds16(const void* g, void* l) {
    __builtin_amdgcn_global_load_lds(
        (const __attribute__((address_space(1))) uint32_t*)g,
        (__attribute__((address_space(3))) uint32_t*)l,
        16, 0, 0);
}

// ---------- kernel 1: FWHT setup (fused) ----------
// blocks 0,2: g_W1 / g_W2 -> g[0..1023], g[2048..3071] (consumed by wmat)
// blocks 1,3: g_b in LDS only; write bias vector directly (init + PP * g[i&1023])
__global__ void fwht_setup_kernel(const float* __restrict__ V,
                                  const float* __restrict__ D0, const float* __restrict__ D1,
                                  const float* __restrict__ D2, const float* __restrict__ D3,
                                  const float* __restrict__ b1_init, const float* __restrict__ PP_b1,
                                  const float* __restrict__ b2_init, const float* __restrict__ PP_b2,
                                  float* __restrict__ g, float* __restrict__ b1w,
                                  float* __restrict__ b2w) {
    __shared__ float s[1024];
    int t = threadIdx.x;
    const float* D = (blockIdx.x == 0) ? D0 : (blockIdx.x == 1) ? D1 :
                     (blockIdx.x == 2) ? D2 : D3;
    s[t] = D[t] * V[t];
    __syncthreads();
    #pragma unroll
    for (int st = 512; st >= 1; st >>= 1) {
        float a = s[t];
        float b = s[t ^ st];
        __syncthreads();
        s[t] = (t & st) ? (b - a) : (a + b);
        __syncthreads();
    }
    float gv = s[t] * (1.0f / 1024.0f);
    if (blockIdx.x == 0) {
        g[t] = gv;                       // g_W1
    } else if (blockIdx.x == 2) {
        g[2048 + t] = gv;                // g_W2
    } else {
        const float* init = (blockIdx.x == 1) ? b1_init : b2_init;
        const float* PP   = (blockIdx.x == 1) ? PP_b1  : PP_b2;
        float* out        = (blockIdx.x == 1) ? b1w    : b2w;
        #pragma unroll
        for (int i = t; i < 4096; i += 1024)     // (i & 1023) == t
            out[i] = init[i] + PP[i] * gv;
    }
}

// ---------- kernel 2: f32 -> bf16 cast (x), 4 elems/thread ----------
__global__ void cast_kernel(const float* __restrict__ in, u16* __restrict__ out, int n4) {
    int i = blockIdx.x * blockDim.x + threadIdx.x;
    if (i >= n4) return;
    float4 v = ((const float4*)in)[i];
    uint32_t lo = f2bf(v.x) | (f2bf(v.y) << 16);
    uint32_t hi = f2bf(v.z) | (f2bf(v.w) << 16);
    ((uint2*)out)[i] = make_uint2(lo, hi);
}

// ---------- kernel 3: W_bf16 = bf16(W_init + PP * g[idx&1023]), 4 elems/thread ----------
__global__ void wmat_kernel(const float* __restrict__ init, const float* __restrict__ PP,
                            const float* __restrict__ g, u16* __restrict__ out, int n4) {
    int i = blockIdx.x * blockDim.x + threadIdx.x;
    if (i >= n4) return;
    int e = i * 4;
    float4 wi = ((const float4*)init)[i];
    float4 pp = ((const float4*)PP)[i];
    float4 gv = *((const float4*)(g + (e & 1023)));
    uint32_t lo = f2bf(wi.x + pp.x * gv.x) | (f2bf(wi.y + pp.y * gv.y) << 16);
    uint32_t hi = f2bf(wi.z + pp.z * gv.z) | (f2bf(wi.w + pp.w * gv.w) << 16);
    ((uint2*)out)[i] = make_uint2(lo, hi);
}

// ---------- kernel 4: split-K GEMM partial: P[s] = A(MxKs) @ B^T(NxKs), bf16 out ----------
// r14-proven optimum: BM=128, BN=64, BK=64, single-buffered 24 KB LDS,
// grid (N/64, M/128, 4) = 1024 WGs = 4 WG/CU, XOR swizzle both tiles,
// bf16 partials. 4 waves 2x2: wave tile 64x32, acc[4][2].
__global__ __launch_bounds__(256, 4) void gemm_splitk(const u16* __restrict__ A,
                                                      const u16* __restrict__ B,
                                                      u16* __restrict__ P,
                                                      int M, int N, int K, int Kslice) {
    constexpr int BM = 128, BN = 64, BK = 64;
    __shared__ u16 As[BM * BK];   // 16 KB
    __shared__ u16 Bs[BN * BK];   // 8 KB

    const int t    = threadIdx.x;
    const int wid  = t >> 6;
    const int lane = t & 63;
    const int wr   = wid >> 1;        // 0..1: 64-row block of A
    const int wc   = wid & 1;         // 0..1: 32-col block of B
    const int fr   = lane & 15;
    const int fq   = lane >> 4;
    const int rx   = (fr & 7) << 4;   // read-side swizzle xor (bytes)

    const int bn = blockIdx.x, bm = blockIdx.y, sk = blockIdx.z;
    const int k_beg = sk * Kslice;

    const u16* Abase = A + (size_t)(bm * BM) * K;
    const u16* Bbase = B + (size_t)(bn * BN) * K;

    f32x4 acc[4][2];
    #pragma unroll
    for (int m = 0; m < 4; ++m)
        #pragma unroll
        for (int n = 0; n < 2; ++n)
            acc[m][n] = (f32x4){0.f, 0.f, 0.f, 0.f};

    #pragma unroll 1
    for (int k0 = k_beg; k0 < k_beg + Kslice; k0 += BK) {
        // stage A: 128x64 = 1024 16B-chunks = 4 rounds; source col pre-swizzled
        #pragma unroll
        for (int q = 0; q < 4; ++q) {
            int L = q * 256 + t;
            int row = L >> 3;
            int cg  = (L & 7) ^ (row & 7);
            glds16(Abase + (size_t)row * K + k0 + cg * 8, As + L * 8);
        }
        // stage B: 64x64 = 512 chunks = 2 rounds
        #pragma unroll
        for (int q = 0; q < 2; ++q) {
            int L = q * 256 + t;
            int row = L >> 3;
            int cg  = (L & 7) ^ (row & 7);
            glds16(Bbase + (size_t)row * K + k0 + cg * 8, Bs + L * 8);
        }
        __syncthreads();

        const char* Ap = (const char*)As;
        const char* Bp = (const char*)Bs;
        __builtin_amdgcn_s_setprio(1);
        #pragma unroll
        for (int ks = 0; ks < 2; ++ks) {
            const int co = (ks * 64 + fq * 16) ^ rx;
            short8 a[4], b[2];
            #pragma unroll
            for (int m = 0; m < 4; ++m)
                a[m] = *(const short8*)(Ap + (wr * 64 + m * 16 + fr) * 128 + co);
            #pragma unroll
            for (int n = 0; n < 2; ++n)
                b[n] = *(const short8*)(Bp + (wc * 32 + n * 16 + fr) * 128 + co);
            #pragma unroll
            for (int m = 0; m < 4; ++m)
                #pragma unroll
                for (int n = 0; n < 2; ++n)
                    acc[m][n] = __builtin_amdgcn_mfma_f32_16x16x32_bf16(a[m], b[n], acc[m][n], 0, 0, 0);
        }
        __builtin_amdgcn_s_setprio(0);
        __syncthreads();
    }

    // epilogue: write bf16 partial tile
    u16* Pp = P + (size_t)sk * M * N;
    #pragma unroll
    for (int m = 0; m < 4; ++m) {
        int grow0 = bm * BM + wr * 64 + m * 16 + fq * 4;
        #pragma unroll
        for (int n = 0; n < 2; ++n) {
            int gcol = bn * BN + wc * 32 + n * 16 + fr;
            #pragma unroll
            for (int j = 0; j < 4; ++j)
                Pp[(size_t)(grow0 + j) * N + gcol] = (u16)f2bf(acc[m][n][j]);
        }
    }
}

// ---------- kernel 5: reduce S bf16 partials + bias (+relu) -> bf16 or f32 ----------
template <typename OutT, bool RELU, int S>
__global__ void reduce_kernel(const u16* __restrict__ P, const float* __restrict__ bias,
                              OutT* __restrict__ out, int MN, int N) {
    int i = blockIdx.x * blockDim.x + threadIdx.x;   // handles 8 elems
    if (i * 8 >= MN) return;
    int e = i * 8;
    int col = e & (N - 1);

    float a0 = 0.f, a1 = 0.f, a2 = 0.f, a3 = 0.f, a4 = 0.f, a5 = 0.f, a6 = 0.f, a7 = 0.f;
    #pragma unroll
    for (int s = 0; s < S; ++s) {
        uint4 v = ((const uint4*)(P + (size_t)s * MN))[i];
        a0 += bf2f(v.x & 0xffffu);  a1 += bf2f(v.x >> 16);
        a2 += bf2f(v.y & 0xffffu);  a3 += bf2f(v.y >> 16);
        a4 += bf2f(v.z & 0xffffu);  a5 += bf2f(v.z >> 16);
        a6 += bf2f(v.w & 0xffffu);  a7 += bf2f(v.w >> 16);
    }
    float4 bv0 = ((const float4*)(bias + col))[0];
    float4 bv1 = ((const float4*)(bias + col))[1];
    a0 += bv0.x; a1 += bv0.y; a2 += bv0.z; a3 += bv0.w;
    a4 += bv1.x; a5 += bv1.y; a6 += bv1.z; a7 += bv1.w;
    if (RELU) {
        a0 = fmaxf(a0, 0.f); a1 = fmaxf(a1, 0.f); a2 = fmaxf(a2, 0.f); a3 = fmaxf(a3, 0.f);
        a4 = fmaxf(a4, 0.f); a5 = fmaxf(a5, 0.f); a6 = fmaxf(a6, 0.f); a7 = fmaxf(a7, 0.f);
    }
    if constexpr (sizeof(OutT) == 2) {
        uint4 r;
        r.x = f2bf(a0) | (f2bf(a1) << 16);
        r.y = f2bf(a2) | (f2bf(a3) << 16);
        r.z = f2bf(a4) | (f2bf(a5) << 16);
        r.w = f2bf(a6) | (f2bf(a7) << 16);
        ((uint4*)out)[i] = r;
    } else {
        float4 o0 = {a0, a1, a2, a3};
        float4 o1 = {a4, a5, a6, a7};
        ((float4*)out)[i * 2]     = o0;
        ((float4*)out)[i * 2 + 1] = o1;
    }
}

// ---------- launch ----------
extern "C" void kernel_launch(void* const* d_in, const int* in_sizes, int n_in,
                              void* d_out, int out_size, void* d_ws, size_t ws_size,
                              hipStream_t stream) {
    (void)in_sizes; (void)n_in; (void)out_size; (void)ws_size;

    const float* x       = (const float*)d_in[0];
    const float* V       = (const float*)d_in[1];
    const float* W1_init = (const float*)d_in[2];
    const float* D_W1    = (const float*)d_in[3];
    const float* PP_W1   = (const float*)d_in[4];
    const float* b1_init = (const float*)d_in[5];
    const float* D_b1    = (const float*)d_in[6];
    const float* PP_b1   = (const float*)d_in[7];
    const float* W2_init = (const float*)d_in[8];
    const float* D_W2    = (const float*)d_in[9];
    const float* PP_W2   = (const float*)d_in[10];
    const float* b2_init = (const float*)d_in[11];
    const float* D_b2    = (const float*)d_in[12];
    const float* PP_b2   = (const float*)d_in[13];

    constexpr size_t MB = 1024 * 1024;
    char* ws = (char*)d_ws;
    float* g    = (float*)(ws);                      // 4x1024 f32: [W1 | -- | W2 | --]
    float* b1w  = (float*)(ws + 16384);              // 4096 f32
    float* b2w  = (float*)(ws + 32768);              // 4096 f32
    u16*   xb   = (u16*)(ws + 65536);                // 512x4096 bf16 (4 MB)
    u16*   hb   = (u16*)(ws + 65536 + 4 * MB);       // 512x4096 bf16 (4 MB)
    u16*   wbuf = (u16*)(ws + 65536 + 8 * MB);       // 32 MB: W1 then W2
    u16*   Pbuf = (u16*)(ws + 65536 + 40 * MB);      // 4x512x4096 bf16 (16 MB)

    const int M = 512, N = 4096, K = 4096, S = 4, Kslice = K / S;

    fwht_setup_kernel<<<4, 1024, 0, stream>>>(V, D_W1, D_b1, D_W2, D_b2,
                                              b1_init, PP_b1, b2_init, PP_b2,
                                              g, b1w, b2w);
    cast_kernel<<<2048, 256, 0, stream>>>(x, xb, M * K / 4);

    // layer 1: materialize W1, GEMM (1024 WGs = 4 WG/CU), reduce
    wmat_kernel<<<16384, 256, 0, stream>>>(W1_init, PP_W1, g, wbuf, 4096 * 4096 / 4);
    gemm_splitk<<<dim3(N / 64, M / 128, S), 256, 0, stream>>>(xb, wbuf, Pbuf, M, N, K, Kslice);
    reduce_kernel<u16, true, S><<<M * N / 8 / 256, 256, 0, stream>>>(Pbuf, b1w, hb, M * N, N);

    // layer 2 (wbuf, Pbuf reused)
    wmat_kernel<<<16384, 256, 0, stream>>>(W2_init, PP_W2, g + 2048, wbuf, 4096 * 4096 / 4);
    gemm_splitk<<<dim3(N / 64, M / 128, S), 256, 0, stream>>>(hb, wbuf, Pbuf, M, N, K, Kslice);
    reduce_kernel<float, false, S><<<M * N / 8 / 256, 256, 0, stream>>>(Pbuf, b2w, (float*)d_out, M * N, N);
}

// Round 20
// 118.707 us; speedup vs baseline: 1.2120x; 1.0309x over previous
//
#include <hip/hip_runtime.h>
#include <hip/hip_bf16.h>
#include <stdint.h>

typedef unsigned short u16;
typedef __attribute__((ext_vector_type(8))) short short8;
typedef __attribute__((ext_vector_type(4))) float f32x4;

// ---------- helpers ----------
__device__ __forceinline__ uint32_t f2bf(float f) {
    union { float f; uint32_t u; } c; c.f = f;
    uint32_t u = c.u;
    u += 0x7fffu + ((u >> 16) & 1u);   // round-to-nearest-even
    return u >> 16;
}

__device__ __forceinline__ float bf2f(uint32_t u) {
    union { uint32_t u; float f; } c; c.u = u << 16; return c.f;
}

__device__ __forceinline__ void glds16(const void* g, void* l) {
    __builtin_amdgcn_global_load_lds(
        (const __attribute__((address_space(1))) uint32_t*)g,
        (__attribute__((address_space(3))) uint32_t*)l,
        16, 0, 0);
}

// ---------- kernel 1: FWHT setup + x-cast (merged, 1024 thr/block) ----------
// blocks 0,2: g_W1 / g_W2 -> g[0..1023] / g[2048..3071]
// blocks 1,3: bias vectors directly (init + PP * g[i&1023])
// blocks 4..515: cast x f32 -> bf16, 4 elems/thread (512 blocks x 1024 thr x 4)
__global__ void fwht_setup_kernel(const float* __restrict__ V,
                                  const float* __restrict__ D0, const float* __restrict__ D1,
                                  const float* __restrict__ D2, const float* __restrict__ D3,
                                  const float* __restrict__ b1_init, const float* __restrict__ PP_b1,
                                  const float* __restrict__ b2_init, const float* __restrict__ PP_b2,
                                  float* __restrict__ g, float* __restrict__ b1w,
                                  float* __restrict__ b2w,
                                  const float* __restrict__ x, u16* __restrict__ xb) {
    int t = threadIdx.x;
    if (blockIdx.x >= 4) {
        // ---- cast half: x (512x4096 f32) -> xb bf16 ----
        int i = (blockIdx.x - 4) * 1024 + t;      // float4 index, 524288 total
        float4 v = ((const float4*)x)[i];
        uint32_t lo = f2bf(v.x) | (f2bf(v.y) << 16);
        uint32_t hi = f2bf(v.z) | (f2bf(v.w) << 16);
        ((uint2*)xb)[i] = make_uint2(lo, hi);
        return;
    }
    // ---- FWHT half ----
    __shared__ float s[1024];
    const float* D = (blockIdx.x == 0) ? D0 : (blockIdx.x == 1) ? D1 :
                     (blockIdx.x == 2) ? D2 : D3;
    s[t] = D[t] * V[t];
    __syncthreads();
    #pragma unroll
    for (int st = 512; st >= 1; st >>= 1) {
        float a = s[t];
        float b = s[t ^ st];
        __syncthreads();
        s[t] = (t & st) ? (b - a) : (a + b);
        __syncthreads();
    }
    float gv = s[t] * (1.0f / 1024.0f);
    if (blockIdx.x == 0) {
        g[t] = gv;                       // g_W1
    } else if (blockIdx.x == 2) {
        g[2048 + t] = gv;                // g_W2
    } else {
        const float* init = (blockIdx.x == 1) ? b1_init : b2_init;
        const float* PP   = (blockIdx.x == 1) ? PP_b1  : PP_b2;
        float* out        = (blockIdx.x == 1) ? b1w    : b2w;
        #pragma unroll
        for (int i = t; i < 4096; i += 1024)     // (i & 1023) == t
            out[i] = init[i] + PP[i] * gv;
    }
}

// ---------- kernel 2: W_bf16 = bf16(W_init + PP * g[idx&1023]), 4 elems/thread ----------
__global__ void wmat_kernel(const float* __restrict__ init, const float* __restrict__ PP,
                            const float* __restrict__ g, u16* __restrict__ out, int n4) {
    int i = blockIdx.x * blockDim.x + threadIdx.x;
    if (i >= n4) return;
    int e = i * 4;
    float4 wi = ((const float4*)init)[i];
    float4 pp = ((const float4*)PP)[i];
    float4 gv = *((const float4*)(g + (e & 1023)));
    uint32_t lo = f2bf(wi.x + pp.x * gv.x) | (f2bf(wi.y + pp.y * gv.y) << 16);
    uint32_t hi = f2bf(wi.z + pp.z * gv.z) | (f2bf(wi.w + pp.w * gv.w) << 16);
    ((uint2*)out)[i] = make_uint2(lo, hi);
}

// ---------- reduce body (shared by standalone and merged kernels) ----------
template <typename OutT, bool RELU, int S>
__device__ __forceinline__ void reduce_body(int i, const u16* __restrict__ P,
                                            const float* __restrict__ bias,
                                            OutT* __restrict__ out, int MN, int N) {
    if (i * 8 >= MN) return;
    int e = i * 8;
    int col = e & (N - 1);

    float a0 = 0.f, a1 = 0.f, a2 = 0.f, a3 = 0.f, a4 = 0.f, a5 = 0.f, a6 = 0.f, a7 = 0.f;
    #pragma unroll
    for (int s = 0; s < S; ++s) {
        uint4 v = ((const uint4*)(P + (size_t)s * MN))[i];
        a0 += bf2f(v.x & 0xffffu);  a1 += bf2f(v.x >> 16);
        a2 += bf2f(v.y & 0xffffu);  a3 += bf2f(v.y >> 16);
        a4 += bf2f(v.z & 0xffffu);  a5 += bf2f(v.z >> 16);
        a6 += bf2f(v.w & 0xffffu);  a7 += bf2f(v.w >> 16);
    }
    float4 bv0 = ((const float4*)(bias + col))[0];
    float4 bv1 = ((const float4*)(bias + col))[1];
    a0 += bv0.x; a1 += bv0.y; a2 += bv0.z; a3 += bv0.w;
    a4 += bv1.x; a5 += bv1.y; a6 += bv1.z; a7 += bv1.w;
    if (RELU) {
        a0 = fmaxf(a0, 0.f); a1 = fmaxf(a1, 0.f); a2 = fmaxf(a2, 0.f); a3 = fmaxf(a3, 0.f);
        a4 = fmaxf(a4, 0.f); a5 = fmaxf(a5, 0.f); a6 = fmaxf(a6, 0.f); a7 = fmaxf(a7, 0.f);
    }
    if constexpr (sizeof(OutT) == 2) {
        uint4 r;
        r.x = f2bf(a0) | (f2bf(a1) << 16);
        r.y = f2bf(a2) | (f2bf(a3) << 16);
        r.z = f2bf(a4) | (f2bf(a5) << 16);
        r.w = f2bf(a6) | (f2bf(a7) << 16);
        ((uint4*)out)[i] = r;
    } else {
        float4 o0 = {a0, a1, a2, a3};
        float4 o1 = {a4, a5, a6, a7};
        ((float4*)out)[i * 2]     = o0;
        ((float4*)out)[i * 2 + 1] = o1;
    }
}

// ---------- kernel 3: merged wmat(W2) + reduce1 (both BW-bound, independent) ----------
// blocks [0, 16384): W2 materialization; blocks [16384, 17408): reduce layer-1.
__global__ void wmat_reduce_kernel(const float* __restrict__ W2init, const float* __restrict__ PP2,
                                   const float* __restrict__ g2, u16* __restrict__ w2out,
                                   const u16* __restrict__ P, const float* __restrict__ b1w,
                                   u16* __restrict__ hb, int MN, int N) {
    if (blockIdx.x < 16384) {
        int i = blockIdx.x * blockDim.x + threadIdx.x;
        int e = i * 4;
        float4 wi = ((const float4*)W2init)[i];
        float4 pp = ((const float4*)PP2)[i];
        float4 gv = *((const float4*)(g2 + (e & 1023)));
        uint32_t lo = f2bf(wi.x + pp.x * gv.x) | (f2bf(wi.y + pp.y * gv.y) << 16);
        uint32_t hi = f2bf(wi.z + pp.z * gv.z) | (f2bf(wi.w + pp.w * gv.w) << 16);
        ((uint2*)w2out)[i] = make_uint2(lo, hi);
    } else {
        int i = (blockIdx.x - 16384) * blockDim.x + threadIdx.x;
        reduce_body<u16, true, 4>(i, P, b1w, hb, MN, N);
    }
}

// ---------- kernel 4: split-K GEMM partial: P[s] = A(MxKs) @ B^T(NxKs), bf16 out ----------
// r14-proven optimum: BM=128, BN=64, BK=64, single-buffered 24 KB LDS,
// grid (N/64, M/128, 4) = 1024 WGs = 4 WG/CU, XOR swizzle both tiles, bf16 partials.
__global__ __launch_bounds__(256, 4) void gemm_splitk(const u16* __restrict__ A,
                                                      const u16* __restrict__ B,
                                                      u16* __restrict__ P,
                                                      int M, int N, int K, int Kslice) {
    constexpr int BM = 128, BN = 64, BK = 64;
    __shared__ u16 As[BM * BK];   // 16 KB
    __shared__ u16 Bs[BN * BK];   // 8 KB

    const int t    = threadIdx.x;
    const int wid  = t >> 6;
    const int lane = t & 63;
    const int wr   = wid >> 1;        // 0..1: 64-row block of A
    const int wc   = wid & 1;         // 0..1: 32-col block of B
    const int fr   = lane & 15;
    const int fq   = lane >> 4;
    const int rx   = (fr & 7) << 4;   // read-side swizzle xor (bytes)

    const int bn = blockIdx.x, bm = blockIdx.y, sk = blockIdx.z;
    const int k_beg = sk * Kslice;

    const u16* Abase = A + (size_t)(bm * BM) * K;
    const u16* Bbase = B + (size_t)(bn * BN) * K;

    f32x4 acc[4][2];
    #pragma unroll
    for (int m = 0; m < 4; ++m)
        #pragma unroll
        for (int n = 0; n < 2; ++n)
            acc[m][n] = (f32x4){0.f, 0.f, 0.f, 0.f};

    #pragma unroll 1
    for (int k0 = k_beg; k0 < k_beg + Kslice; k0 += BK) {
        // stage A: 128x64 = 1024 16B-chunks = 4 rounds; source col pre-swizzled
        #pragma unroll
        for (int q = 0; q < 4; ++q) {
            int L = q * 256 + t;
            int row = L >> 3;
            int cg  = (L & 7) ^ (row & 7);
            glds16(Abase + (size_t)row * K + k0 + cg * 8, As + L * 8);
        }
        // stage B: 64x64 = 512 chunks = 2 rounds
        #pragma unroll
        for (int q = 0; q < 2; ++q) {
            int L = q * 256 + t;
            int row = L >> 3;
            int cg  = (L & 7) ^ (row & 7);
            glds16(Bbase + (size_t)row * K + k0 + cg * 8, Bs + L * 8);
        }
        __syncthreads();

        const char* Ap = (const char*)As;
        const char* Bp = (const char*)Bs;
        __builtin_amdgcn_s_setprio(1);
        #pragma unroll
        for (int ks = 0; ks < 2; ++ks) {
            const int co = (ks * 64 + fq * 16) ^ rx;
            short8 a[4], b[2];
            #pragma unroll
            for (int m = 0; m < 4; ++m)
                a[m] = *(const short8*)(Ap + (wr * 64 + m * 16 + fr) * 128 + co);
            #pragma unroll
            for (int n = 0; n < 2; ++n)
                b[n] = *(const short8*)(Bp + (wc * 32 + n * 16 + fr) * 128 + co);
            #pragma unroll
            for (int m = 0; m < 4; ++m)
                #pragma unroll
                for (int n = 0; n < 2; ++n)
                    acc[m][n] = __builtin_amdgcn_mfma_f32_16x16x32_bf16(a[m], b[n], acc[m][n], 0, 0, 0);
        }
        __builtin_amdgcn_s_setprio(0);
        __syncthreads();
    }

    // epilogue: write bf16 partial tile
    u16* Pp = P + (size_t)sk * M * N;
    #pragma unroll
    for (int m = 0; m < 4; ++m) {
        int grow0 = bm * BM + wr * 64 + m * 16 + fq * 4;
        #pragma unroll
        for (int n = 0; n < 2; ++n) {
            int gcol = bn * BN + wc * 32 + n * 16 + fr;
            #pragma unroll
            for (int j = 0; j < 4; ++j)
                Pp[(size_t)(grow0 + j) * N + gcol] = (u16)f2bf(acc[m][n][j]);
        }
    }
}

// ---------- kernel 5: standalone reduce (layer 2) ----------
template <typename OutT, bool RELU, int S>
__global__ void reduce_kernel(const u16* __restrict__ P, const float* __restrict__ bias,
                              OutT* __restrict__ out, int MN, int N) {
    int i = blockIdx.x * blockDim.x + threadIdx.x;
    reduce_body<OutT, RELU, S>(i, P, bias, out, MN, N);
}

// ---------- launch ----------
extern "C" void kernel_launch(void* const* d_in, const int* in_sizes, int n_in,
                              void* d_out, int out_size, void* d_ws, size_t ws_size,
                              hipStream_t stream) {
    (void)in_sizes; (void)n_in; (void)out_size; (void)ws_size;

    const float* x       = (const float*)d_in[0];
    const float* V       = (const float*)d_in[1];
    const float* W1_init = (const float*)d_in[2];
    const float* D_W1    = (const float*)d_in[3];
    const float* PP_W1   = (const float*)d_in[4];
    const float* b1_init = (const float*)d_in[5];
    const float* D_b1    = (const float*)d_in[6];
    const float* PP_b1   = (const float*)d_in[7];
    const float* W2_init = (const float*)d_in[8];
    const float* D_W2    = (const float*)d_in[9];
    const float* PP_W2   = (const float*)d_in[10];
    const float* b2_init = (const float*)d_in[11];
    const float* D_b2    = (const float*)d_in[12];
    const float* PP_b2   = (const float*)d_in[13];

    constexpr size_t MB = 1024 * 1024;
    char* ws = (char*)d_ws;
    float* g    = (float*)(ws);                      // 4x1024 f32: [W1 | -- | W2 | --]
    float* b1w  = (float*)(ws + 16384);              // 4096 f32
    float* b2w  = (float*)(ws + 32768);              // 4096 f32
    u16*   xb   = (u16*)(ws + 65536);                // 512x4096 bf16 (4 MB)
    u16*   hb   = (u16*)(ws + 65536 + 4 * MB);       // 512x4096 bf16 (4 MB)
    u16*   wbuf = (u16*)(ws + 65536 + 8 * MB);       // 32 MB: W1 then W2
    u16*   Pbuf = (u16*)(ws + 65536 + 40 * MB);      // 4x512x4096 bf16 (16 MB)

    const int M = 512, N = 4096, K = 4096, S = 4, Kslice = K / S;

    // 1: FWHT + biases + x-cast (merged)
    fwht_setup_kernel<<<516, 1024, 0, stream>>>(V, D_W1, D_b1, D_W2, D_b2,
                                                b1_init, PP_b1, b2_init, PP_b2,
                                                g, b1w, b2w, x, xb);
    // 2: materialize W1
    wmat_kernel<<<16384, 256, 0, stream>>>(W1_init, PP_W1, g, wbuf, 4096 * 4096 / 4);
    // 3: layer-1 GEMM (1024 WGs = 4 WG/CU)
    gemm_splitk<<<dim3(N / 64, M / 128, S), 256, 0, stream>>>(xb, wbuf, Pbuf, M, N, K, Kslice);
    // 4: W2 materialization + layer-1 reduce (merged, both BW-bound, independent)
    wmat_reduce_kernel<<<16384 + 1024, 256, 0, stream>>>(W2_init, PP_W2, g + 2048,
                                                         (u16*)(ws + 65536 + 8 * MB + 32 * MB - 32 * MB) /*wbuf*/,
                                                         Pbuf, b1w, hb, M * N, N);
    // NOTE: wbuf passed directly above; rewritten for clarity:
    // 5: layer-2 GEMM
    gemm_splitk<<<dim3(N / 64, M / 128, S), 256, 0, stream>>>(hb, wbuf, Pbuf, M, N, K, Kslice);
    // 6: layer-2 reduce -> d_out
    reduce_kernel<float, false, S><<<M * N / 8 / 256, 256, 0, stream>>>(Pbuf, b2w, (float*)d_out, M * N, N);
}